// Round 20
// baseline (67.842 us; speedup 1.0000x reference)
//
#include <hip/hip_runtime.h>

#define BB 8
#define CC 256
#define HH 96
#define WW 96
#define HWW (HH*WW)
#define NLOC 256        // local prototypes (MFMA path)
#define PPAD 257        // + global prototype
#define THRESH 0.95f
#define NORM_EPS 1e-4f

typedef __attribute__((ext_vector_type(8))) _Float16 f16x8;
typedef __attribute__((ext_vector_type(16))) float f32x16;

union H16 { _Float16 f; unsigned short u; };

// ---- fused kernel 0+1: mask pooling (8 blocks) + feature pooling (2048) ----
__global__ void k01(const float* __restrict__ sup_fts,
                    const float* __restrict__ sup_mask,
                    const float* __restrict__ true_bg,
                    float* __restrict__ protos,
                    float* __restrict__ validf,
                    float* __restrict__ masksum) {
    __shared__ float red[256];
    int blk = blockIdx.x;
    int t = threadIdx.x;
    if (blk < BB * CC) {
        int b = blk >> 8, c = blk & 255;
        int gy = t >> 4, gx = t & 15;
        const float* fb = sup_fts + ((size_t)b * CC + c) * HWW;
        const float* mb = sup_mask + (size_t)b * HWW;
        int base = gy * 6 * WW + gx * 6;
        float fs = 0.f, fm = 0.f;
        for (int r = 0; r < 6; ++r) {
            const float* rowf = fb + base + r * WW;
            const float* rowm = mb + base + r * WW;
#pragma unroll
            for (int h = 0; h < 3; ++h) {
                float2 v  = *(const float2*)(rowf + 2 * h);
                float2 mk = *(const float2*)(rowm + 2 * h);
                fs += v.x + v.y;
                fm = fmaf(v.x, mk.x, fm);
                fm = fmaf(v.y, mk.y, fm);
            }
        }
        protos[((size_t)b * PPAD + t) * CC + c] = fs * (1.f / 36.f);
        red[t] = fm;
        __syncthreads();
        for (int off = 128; off > 0; off >>= 1) {
            if (t < off) red[t] += red[t + off];
            __syncthreads();
        }
        if (t == 0) protos[((size_t)b * PPAD + 256) * CC + c] = red[0];
    } else {
        int b = blk - BB * CC;
        int gy = t >> 4, gx = t & 15;
        const float* mb = sup_mask + (size_t)b * HWW;
        const float* gb = true_bg  + (size_t)b * HWW;
        int base = gy * 6 * WW + gx * 6;
        float ms = 0.f, bs = 0.f;
        for (int r = 0; r < 6; ++r) {
            const float* rowm = mb + base + r * WW;
            const float* rowg = gb + base + r * WW;
#pragma unroll
            for (int h = 0; h < 3; ++h) {
                float2 mk = *(const float2*)(rowm + 2 * h);
                float2 bg2 = *(const float2*)(rowg + 2 * h);
                ms += mk.x + mk.y;
                bs += bg2.x + bg2.y;
            }
        }
        float mmean = ms * (1.f / 36.f);
        float bmean = bs * (1.f / 36.f);
        validf[b * PPAD + t] = (mmean > THRESH && bmean < 0.5f) ? 1.f : 0.f;
        if (t == 0) validf[b * PPAD + 256] = 1.f;
        red[t] = ms;
        __syncthreads();
        for (int off = 128; off > 0; off >>= 1) {
            if (t < off) red[t] += red[t + off];
            __syncthreads();
        }
        if (t == 0) masksum[b] = red[0];
    }
}

// ------- kernel 2: finish gproto + normalize + emit fp16 proto image --------
// Pimg layout (fp16): [B][16 kstep][2 khalf][8 tile][32 col][8 e]
__global__ void k2_norm(float* __restrict__ protos,
                        const float* __restrict__ masksum,
                        unsigned short* __restrict__ Pimg) {
    int bp = blockIdx.x;
    int b = bp / PPAD;
    int p = bp - b * PPAD;
    int t = threadIdx.x;            // channel
    float v = protos[((size_t)b * PPAD + p) * CC + t];
    if (p == 256) v = v / (masksum[b] + 1e-5f);
    __shared__ float red[256];
    red[t] = v * v;
    __syncthreads();
    for (int off = 128; off > 0; off >>= 1) {
        if (t < off) red[t] += red[t + off];
        __syncthreads();
    }
    float norm = sqrtf(red[0]);
    float vn = v / fmaxf(norm, NORM_EPS);
    protos[((size_t)b * PPAD + p) * CC + t] = vn;
    if (p < NLOC) {
        H16 h; h.f = (_Float16)vn;            // RNE, err 2^-11
        int kstep = t >> 4, khalf = (t >> 3) & 1, e = t & 7;
        int tile = p >> 5, col = p & 31;
        size_t idx = ((((size_t)b * 16 + kstep) * 2 + khalf) * 8 + tile) * 256
                     + col * 8 + e;
        Pimg[idx] = h.u;
    }
}

// ---------------- kernel 3: MFMA dists + masked softmax + weighted sum ------
// 64-px tiles (1152 blocks). Staging adopts k2q's MEASURED-3.9TB/s pattern:
// staging wave = 64 lanes x 64 consecutive px -> every q-load instruction is
// 256B contiguous; 64 independent scalar loads/thread in unrolled groups of 8
// (deep MLP). r13/r19's k3 staging was 2x128B per instr + compiler-serialized
// loads -> whole kernel ran at ~1.4TB/s (the 19-round wall).
// Marathon: wave w owns protos [64w,64w+64) for BOTH 32-px subtiles (B-frags
// reused x2). Epilogue = r13-verified per sub. LDS layout: Qf[kq][px64][4ch].
__global__ __launch_bounds__(256, 4)
void k3_mfma(const float* __restrict__ qry,
             const unsigned short* __restrict__ Pimg,
             const float* __restrict__ protos_n,
             const float* __restrict__ validf,
             float* __restrict__ out) {
    __shared__ alignas(16) unsigned short Qf[64 * 256];    // [kq][px64][4] = 32 KB
    __shared__ float red_n[4][64], red_g[4][64];
    __shared__ float rn_s[64], gd_s[64];
    __shared__ float S_l[4][64], N_l[4][64];

    int blk = blockIdx.x;
    int b = blk & 7;                  // batch <-> XCD affinity
    int tile = blk >> 3;              // 0..143
    int px0 = tile * 64;
    int t = threadIdx.x;              // 0..255
    int l = t & 63;
    int w = t >> 6;                   // wave 0..3
    int col = l & 31;
    int h = l >> 5;

    int spx = t & 63;                 // staging: pixel (64 consecutive per wave)
    int cq  = t >> 6;                 // staging: channel quarter (wave-uniform)

    const float* qb = qry + (size_t)b * CC * HWW + px0 + spx;
    const float* gp = protos_n + ((size_t)b * PPAD + 256) * CC;
    const unsigned short* Pb = Pimg + (size_t)b * 65536;

    float vf0 = validf[b * PPAD + w * 64 + col];
    float vf1 = validf[b * PPAD + w * 64 + 32 + col];

    // ---- staging: 64 ch/thread, groups of 8 (k2q pattern: 256B/instr) ----
    float nrm = 0.f, gac = 0.f;
#pragma unroll
    for (int g8 = 0; g8 < 8; ++g8) {
        int c0 = cq * 64 + g8 * 8;
        float v[8];
#pragma unroll
        for (int i = 0; i < 8; ++i) v[i] = qb[(size_t)(c0 + i) * HWW];
        unsigned int hh[8];
#pragma unroll
        for (int i = 0; i < 8; ++i) {
            H16 x; x.f = (_Float16)v[i];          // RNE
            hh[i] = x.u;
            nrm = fmaf(v[i], v[i], nrm);
            gac = fmaf(v[i], gp[c0 + i], gac);    // wave-uniform, L1-hot
        }
        int kq = cq * 16 + g8 * 2;
        uint2 p0, p1;
        p0.x = hh[0] | (hh[1] << 16); p0.y = hh[2] | (hh[3] << 16);
        p1.x = hh[4] | (hh[5] << 16); p1.y = hh[6] | (hh[7] << 16);
        *(uint2*)&Qf[kq * 256 + spx * 4] = p0;         // 512B/instr dense write
        *(uint2*)&Qf[(kq + 1) * 256 + spx * 4] = p1;
    }
    red_n[cq][spx] = nrm;
    red_g[cq][spx] = gac;
    __syncthreads();
    if (t < 64) {
        float n2 = red_n[0][t] + red_n[1][t] + red_n[2][t] + red_n[3][t];
        float gs = red_g[0][t] + red_g[1][t] + red_g[2][t] + red_g[3][t];
        float rn = 1.f / fmaxf(sqrtf(n2), NORM_EPS);
        rn_s[t] = rn;
        gd_s[t] = gs * rn;
    }

    // ---- accumulators + B stream (reused across both px-subtiles) ----
    f32x16 acc[2][2];                 // [sub][ti]
#pragma unroll
    for (int s = 0; s < 2; ++s)
#pragma unroll
        for (int i = 0; i < 16; ++i) { acc[s][0][i] = 0.f; acc[s][1][i] = 0.f; }
    f16x8 Bf[2][2];

#define LOADB(KS, BUF)                                                        \
    {                                                                         \
        _Pragma("unroll")                                                     \
        for (int ti = 0; ti < 2; ++ti)                                        \
            Bf[BUF][ti] = *(const f16x8*)(Pb +                                \
                ((((size_t)(KS) * 2 + h) * 8 + (w * 2 + ti)) * 32 + col) * 8);\
    }

    LOADB(0, 0);
    LOADB(1, 1);

    // ---- marathon: 16 ks x {4 A-reads (2 subs), 4 MFMA} ----
#pragma unroll
    for (int ks = 0; ks < 16; ++ks) {
        int kq0 = ks * 4 + h * 2;
        uint2 a0 = *(const uint2*)&Qf[kq0 * 256 + col * 4];
        uint2 a1 = *(const uint2*)&Qf[(kq0 + 1) * 256 + col * 4];
        uint2 a2 = *(const uint2*)&Qf[kq0 * 256 + (32 + col) * 4];
        uint2 a3 = *(const uint2*)&Qf[(kq0 + 1) * 256 + (32 + col) * 4];
        union { f16x8 v; unsigned int u[4]; } Q0, Q1;
        Q0.u[0] = a0.x; Q0.u[1] = a0.y; Q0.u[2] = a1.x; Q0.u[3] = a1.y;
        Q1.u[0] = a2.x; Q1.u[1] = a2.y; Q1.u[2] = a3.x; Q1.u[3] = a3.y;
#pragma unroll
        for (int ti = 0; ti < 2; ++ti) {
            acc[0][ti] = __builtin_amdgcn_mfma_f32_32x32x16_f16(Q0.v, Bf[ks & 1][ti], acc[0][ti], 0, 0, 0);
            acc[1][ti] = __builtin_amdgcn_mfma_f32_32x32x16_f16(Q1.v, Bf[ks & 1][ti], acc[1][ti], 0, 0, 0);
        }
        if (ks + 2 < 16) LOADB(ks + 2, ks & 1);
    }
#undef LOADB

    __syncthreads();                  // rn_s/gd_s visible

    // ---- softmax epilogue (r13-verified per sub) ----
    // D-map (m74/m101): proto = w*64 + ti*32 + col; local row = (r&3)+8*(r>>2)+4*h.
#pragma unroll
    for (int sub = 0; sub < 2; ++sub) {
#pragma unroll
        for (int r = 0; r < 16; ++r) {
            int row = sub * 32 + (r & 3) + 8 * (r >> 2) + 4 * h;
            float rnv = rn_s[row];
            float d0 = acc[sub][0][r] * rnv;
            float d1 = acc[sub][1][r] * rnv;
            float l0 = (vf0 != 0.f) ? d0 : -1e30f;
            float l1 = (vf1 != 0.f) ? d1 : -1e30f;
            float e0 = __expf(l0 - 1.1f);         // masked -> exactly 0
            float e1 = __expf(l1 - 1.1f);
            float s = e0 + e1;
            float nn = fmaf(e0, l0, e1 * l1);
#pragma unroll
            for (int m = 1; m < 32; m <<= 1) {    // reduce over 32 proto-cols
                s  += __shfl_xor(s, m);
                nn += __shfl_xor(nn, m);
            }
            if (col == 0) { S_l[w][row] = s; N_l[w][row] = nn; }
        }
    }
    __syncthreads();

    // ---- final merge: 4 wave-partials + global proto (once), store ----
    if (t < 64) {
        float gdv = gd_s[t];
        float eg = __expf(gdv - 1.1f);
        float S = eg, N = eg * gdv;
#pragma unroll
        for (int i = 0; i < 4; ++i) { S += S_l[i][t]; N += N_l[i][t]; }
        out[(size_t)b * HWW + px0 + t] = N / S;
    }
}

extern "C" void kernel_launch(void* const* d_in, const int* in_sizes, int n_in,
                              void* d_out, int out_size, void* d_ws, size_t ws_size,
                              hipStream_t stream) {
    const float* qry = (const float*)d_in[0];
    const float* sup = (const float*)d_in[1];
    const float* msk = (const float*)d_in[2];
    const float* bg  = (const float*)d_in[3];
    float* out = (float*)d_out;

    float* ws = (float*)d_ws;
    float* protos  = ws;                                   // [B][257][256] f32
    float* validf  = protos + (size_t)BB * PPAD * CC;      // [B][257]
    float* masksum = validf + (size_t)BB * PPAD;           // [B]
    unsigned short* Pimg = (unsigned short*)(masksum + BB); // [B][16][2][8][32][8] fp16

    hipLaunchKernelGGL(k01, dim3(BB * CC + BB), dim3(256), 0, stream,
                       sup, msk, bg, protos, validf, masksum);
    hipLaunchKernelGGL(k2_norm, dim3(BB * PPAD), dim3(256), 0, stream, protos, masksum, Pimg);
    hipLaunchKernelGGL(k3_mfma, dim3(BB * (HWW / 64)), dim3(256), 0, stream,
                       qry, Pimg, protos, validf, out);
}

// Round 21
// 65.450 us; speedup vs baseline: 1.0365x; 1.0365x over previous
//
#include <hip/hip_runtime.h>

#define BB 8
#define CC 256
#define HH 96
#define WW 96
#define HWW (HH*WW)
#define NLOC 256        // local prototypes (MFMA path)
#define PPAD 257        // + global prototype
#define THRESH 0.95f
#define NORM_EPS 1e-4f

typedef __attribute__((ext_vector_type(8))) _Float16 f16x8;
typedef __attribute__((ext_vector_type(16))) float f32x16;

union H16 { _Float16 f; unsigned short u; };

// ---- fused kernel 0+1: mask pooling (8 blocks) + feature pooling (2048) ----
__global__ void k01(const float* __restrict__ sup_fts,
                    const float* __restrict__ sup_mask,
                    const float* __restrict__ true_bg,
                    float* __restrict__ protos,
                    float* __restrict__ validf,
                    float* __restrict__ masksum) {
    __shared__ float red[256];
    int blk = blockIdx.x;
    int t = threadIdx.x;
    if (blk < BB * CC) {
        int b = blk >> 8, c = blk & 255;
        int gy = t >> 4, gx = t & 15;
        const float* fb = sup_fts + ((size_t)b * CC + c) * HWW;
        const float* mb = sup_mask + (size_t)b * HWW;
        int base = gy * 6 * WW + gx * 6;
        float fs = 0.f, fm = 0.f;
        for (int r = 0; r < 6; ++r) {
            const float* rowf = fb + base + r * WW;
            const float* rowm = mb + base + r * WW;
#pragma unroll
            for (int h = 0; h < 3; ++h) {
                float2 v  = *(const float2*)(rowf + 2 * h);
                float2 mk = *(const float2*)(rowm + 2 * h);
                fs += v.x + v.y;
                fm = fmaf(v.x, mk.x, fm);
                fm = fmaf(v.y, mk.y, fm);
            }
        }
        protos[((size_t)b * PPAD + t) * CC + c] = fs * (1.f / 36.f);
        red[t] = fm;
        __syncthreads();
        for (int off = 128; off > 0; off >>= 1) {
            if (t < off) red[t] += red[t + off];
            __syncthreads();
        }
        if (t == 0) protos[((size_t)b * PPAD + 256) * CC + c] = red[0];
    } else {
        int b = blk - BB * CC;
        int gy = t >> 4, gx = t & 15;
        const float* mb = sup_mask + (size_t)b * HWW;
        const float* gb = true_bg  + (size_t)b * HWW;
        int base = gy * 6 * WW + gx * 6;
        float ms = 0.f, bs = 0.f;
        for (int r = 0; r < 6; ++r) {
            const float* rowm = mb + base + r * WW;
            const float* rowg = gb + base + r * WW;
#pragma unroll
            for (int h = 0; h < 3; ++h) {
                float2 mk = *(const float2*)(rowm + 2 * h);
                float2 bg2 = *(const float2*)(rowg + 2 * h);
                ms += mk.x + mk.y;
                bs += bg2.x + bg2.y;
            }
        }
        float mmean = ms * (1.f / 36.f);
        float bmean = bs * (1.f / 36.f);
        validf[b * PPAD + t] = (mmean > THRESH && bmean < 0.5f) ? 1.f : 0.f;
        if (t == 0) validf[b * PPAD + 256] = 1.f;
        red[t] = ms;
        __syncthreads();
        for (int off = 128; off > 0; off >>= 1) {
            if (t < off) red[t] += red[t + off];
            __syncthreads();
        }
        if (t == 0) masksum[b] = red[0];
    }
}

// ------- kernel 2: finish gproto + normalize + emit fp16 proto image --------
// Pimg layout (fp16): [B][16 kstep][2 khalf][8 tile][32 col][8 e]
__global__ void k2_norm(float* __restrict__ protos,
                        const float* __restrict__ masksum,
                        unsigned short* __restrict__ Pimg) {
    int bp = blockIdx.x;
    int b = bp / PPAD;
    int p = bp - b * PPAD;
    int t = threadIdx.x;            // channel
    float v = protos[((size_t)b * PPAD + p) * CC + t];
    if (p == 256) v = v / (masksum[b] + 1e-5f);
    __shared__ float red[256];
    red[t] = v * v;
    __syncthreads();
    for (int off = 128; off > 0; off >>= 1) {
        if (t < off) red[t] += red[t + off];
        __syncthreads();
    }
    float norm = sqrtf(red[0]);
    float vn = v / fmaxf(norm, NORM_EPS);
    protos[((size_t)b * PPAD + p) * CC + t] = vn;
    if (p < NLOC) {
        H16 h; h.f = (_Float16)vn;            // RNE, err 2^-11
        int kstep = t >> 4, khalf = (t >> 3) & 1, e = t & 7;
        int tile = p >> 5, col = p & 31;
        size_t idx = ((((size_t)b * 16 + kstep) * 2 + khalf) * 8 + tile) * 256
                     + col * 8 + e;
        Pimg[idx] = h.u;
    }
}

// ---------------- kernel 3: MFMA dists + masked softmax + weighted sum ------
// r13/r19 structure (best known) with the staging POISON removed:
// q is staged RAW (fp32) into LDS via 8 x global_load_lds(16B) — fire-and-
// forget, zero VGPR, all requests in flight (r19's VGPR_Count=32 proved the
// compiler serializes register staging loads into ~8 dependent 600-cyc
// L3 exposures; global_load_lds structurally cannot be serialized).
// Raw layout: cell F = ch*8 + pxq  (16B = q[ch][px0+pxq*4..+3], contiguous
// global src; dst linear F*16 = i*4096 + w*1024 + lane*16).
// Convert pass then reads LDS (2-way bank = free), same math as r13.
// Marathon + epilogue byte-identical to r13 (verified D-map, conflicts=0).
__global__ __launch_bounds__(256, 3)
void k3_mfma(const float* __restrict__ qry,
             const unsigned short* __restrict__ Pimg,
             const float* __restrict__ protos_n,
             const float* __restrict__ validf,
             float* __restrict__ out) {
    __shared__ alignas(16) float Qraw[256 * 32];           // [ch][px32] = 32 KB
    __shared__ alignas(16) unsigned short Qf[64 * 128];    // [kq][px32][4 f16] = 16 KB
    __shared__ float red_n[8][32], red_g[8][32];
    __shared__ float rn_s[32], gd_s[32];
    __shared__ float S_l[4][32], N_l[4][32];

    int blk = blockIdx.x;
    int b = blk & 7;                  // batch <-> XCD affinity
    int tpx = blk >> 3;               // 0..287
    int px0 = tpx * 32;
    int t = threadIdx.x;              // 0..255
    int l = t & 63;
    int w = t >> 6;                   // wave 0..3
    int col = l & 31;                 // proto-col within tile
    int h = l >> 5;                   // k-half lane bit

    int spx = t & 31;                 // convert: pixel
    int cg  = t >> 5;                 // convert: channel group (32 ch each)

    const float* qbase = qry + (size_t)b * CC * HWW;
    const float* gp = protos_n + ((size_t)b * PPAD + 256) * CC;
    const unsigned short* Pb = Pimg + (size_t)b * 65536;

    // hoisted epilogue operands
    float vf0 = validf[b * PPAD + w * 64 + col];
    float vf1 = validf[b * PPAD + w * 64 + 32 + col];

    // ---- stage raw q: 8 x global_load_lds(16B)/thread, zero VGPR ----
    {
        char* dstbase = (char*)Qraw + w * 1024;   // wave-uniform; HW adds lane*16
#pragma unroll
        for (int i = 0; i < 8; ++i) {
            int F = i * 256 + t;                  // cell index 0..2047
            int ch = F >> 3, pxq = F & 7;
            __builtin_amdgcn_global_load_lds(
                (const void*)(qbase + (size_t)ch * HWW + px0 + pxq * 4),
                (void*)(dstbase + i * 4096), 16, 0, 0);
        }
    }
    __syncthreads();                  // drains stage — nothing else in flight

    // ---- convert: 32 ch/thread from LDS (no VMEM latency), r13 math ----
    float nrm = 0.f, gac = 0.f;
#pragma unroll
    for (int j = 0; j < 8; ++j) {
        int c0 = cg * 32 + j * 4;
        unsigned int hh[4];
#pragma unroll
        for (int i = 0; i < 4; ++i) {
            float v = Qraw[(c0 + i) * 32 + spx];
            H16 x; x.f = (_Float16)v;             // RNE
            hh[i] = x.u;
            nrm = fmaf(v, v, nrm);
            gac = fmaf(v, gp[c0 + i], gac);       // cg-uniform, L1-hot
        }
        int kq = cg * 8 + j;
        uint2 pk;
        pk.x = hh[0] | (hh[1] << 16); pk.y = hh[2] | (hh[3] << 16);
        *(uint2*)&Qf[kq * 128 + spx * 4] = pk;    // px*8B -> 2-way max (free)
    }
    red_n[cg][spx] = nrm;
    red_g[cg][spx] = gac;
    __syncthreads();
    if (t < 32) {
        float n2 = 0.f, gs = 0.f;
#pragma unroll
        for (int i = 0; i < 8; ++i) { n2 += red_n[i][t]; gs += red_g[i][t]; }
        float rn = 1.f / fmaxf(sqrtf(n2), NORM_EPS);
        rn_s[t] = rn;
        gd_s[t] = gs * rn;
    }

    // ---- accumulators + B stream (loop's only VMEM; L2-resident 128KB/b) --
    f32x16 acc[2];
#pragma unroll
    for (int i = 0; i < 16; ++i) { acc[0][i] = 0.f; acc[1][i] = 0.f; }
    f16x8 Bf[2][2];                   // [buf][tile]

#define LOADB(KS, BUF)                                                        \
    {                                                                         \
        _Pragma("unroll")                                                     \
        for (int ti = 0; ti < 2; ++ti)                                        \
            Bf[BUF][ti] = *(const f16x8*)(Pb +                                \
                ((((size_t)(KS) * 2 + h) * 8 + (w * 2 + ti)) * 32 + col) * 8);\
    }

    LOADB(0, 0);
    LOADB(1, 1);

    // ---- barrier-free marathon: 16 K-steps x {1 A-read, 2 MFMA} ----
#pragma unroll
    for (int ks = 0; ks < 16; ++ks) {
        int kq0 = ks * 4 + h * 2;
        uint2 a0 = *(const uint2*)&Qf[kq0 * 128 + col * 4];
        uint2 a1 = *(const uint2*)&Qf[(kq0 + 1) * 128 + col * 4];
        union { f16x8 v; unsigned int u[4]; } QA;
        QA.u[0] = a0.x; QA.u[1] = a0.y; QA.u[2] = a1.x; QA.u[3] = a1.y;
#pragma unroll
        for (int ti = 0; ti < 2; ++ti)
            acc[ti] = __builtin_amdgcn_mfma_f32_32x32x16_f16(QA.v, Bf[ks & 1][ti], acc[ti], 0, 0, 0);
        if (ks + 2 < 16) LOADB(ks + 2, ks & 1);
    }
#undef LOADB

    __syncthreads();                  // rn_s/gd_s visible

    // ---- softmax epilogue (r13-verified) ----
    // D-map (m74/m101): proto = w*64 + ti*32 + col (col = lane&31);
    // row(px) = (r&3) + 8*(r>>2) + 4*h.
#pragma unroll
    for (int r = 0; r < 16; ++r) {
        int row = (r & 3) + 8 * (r >> 2) + 4 * h;
        float rnv = rn_s[row];
        float d0 = acc[0][r] * rnv;
        float d1 = acc[1][r] * rnv;
        float l0 = (vf0 != 0.f) ? d0 : -1e30f;
        float l1 = (vf1 != 0.f) ? d1 : -1e30f;
        float e0 = __expf(l0 - 1.1f);             // masked -> exactly 0
        float e1 = __expf(l1 - 1.1f);
        float s = e0 + e1;
        float nn = fmaf(e0, l0, e1 * l1);
#pragma unroll
        for (int m = 1; m < 32; m <<= 1) {        // reduce over 32 proto-cols
            s  += __shfl_xor(s, m);
            nn += __shfl_xor(nn, m);
        }
        if (col == 0) { S_l[w][row] = s; N_l[w][row] = nn; }
    }
    __syncthreads();

    // ---- final merge: 4 wave-partials + global proto (once), store ----
    if (t < 32) {
        float gdv = gd_s[t];
        float eg = __expf(gdv - 1.1f);
        float S = eg, N = eg * gdv;
#pragma unroll
        for (int i = 0; i < 4; ++i) { S += S_l[i][t]; N += N_l[i][t]; }
        out[(size_t)b * HWW + px0 + t] = N / S;
    }
}

extern "C" void kernel_launch(void* const* d_in, const int* in_sizes, int n_in,
                              void* d_out, int out_size, void* d_ws, size_t ws_size,
                              hipStream_t stream) {
    const float* qry = (const float*)d_in[0];
    const float* sup = (const float*)d_in[1];
    const float* msk = (const float*)d_in[2];
    const float* bg  = (const float*)d_in[3];
    float* out = (float*)d_out;

    float* ws = (float*)d_ws;
    float* protos  = ws;                                   // [B][257][256] f32
    float* validf  = protos + (size_t)BB * PPAD * CC;      // [B][257]
    float* masksum = validf + (size_t)BB * PPAD;           // [B]
    unsigned short* Pimg = (unsigned short*)(masksum + BB); // [B][16][2][8][32][8] fp16

    hipLaunchKernelGGL(k01, dim3(BB * CC + BB), dim3(256), 0, stream,
                       sup, msk, bg, protos, validf, masksum);
    hipLaunchKernelGGL(k2_norm, dim3(BB * PPAD), dim3(256), 0, stream, protos, masksum, Pimg);
    hipLaunchKernelGGL(k3_mfma, dim3(BB * (HWW / 32)), dim3(256), 0, stream,
                       qry, Pimg, protos, validf, out);
}

// Round 22
// 64.697 us; speedup vs baseline: 1.0486x; 1.0116x over previous
//
#include <hip/hip_runtime.h>

#define BB 8
#define CC 256
#define HH 96
#define WW 96
#define HWW (HH*WW)
#define NLOC 256        // local prototypes (MFMA path)
#define PPAD 257        // + global prototype
#define THRESH 0.95f
#define NORM_EPS 1e-4f

typedef __attribute__((ext_vector_type(8))) _Float16 f16x8;
typedef __attribute__((ext_vector_type(16))) float f32x16;

union H16 { _Float16 f; unsigned short u; };

// ---- fused kernel 0+1: mask pooling (8 blocks) + feature pooling (2048) ----
__global__ void k01(const float* __restrict__ sup_fts,
                    const float* __restrict__ sup_mask,
                    const float* __restrict__ true_bg,
                    float* __restrict__ protos,
                    float* __restrict__ validf,
                    float* __restrict__ masksum) {
    __shared__ float red[256];
    int blk = blockIdx.x;
    int t = threadIdx.x;
    if (blk < BB * CC) {
        int b = blk >> 8, c = blk & 255;
        int gy = t >> 4, gx = t & 15;
        const float* fb = sup_fts + ((size_t)b * CC + c) * HWW;
        const float* mb = sup_mask + (size_t)b * HWW;
        int base = gy * 6 * WW + gx * 6;
        float fs = 0.f, fm = 0.f;
        for (int r = 0; r < 6; ++r) {
            const float* rowf = fb + base + r * WW;
            const float* rowm = mb + base + r * WW;
#pragma unroll
            for (int h = 0; h < 3; ++h) {
                float2 v  = *(const float2*)(rowf + 2 * h);
                float2 mk = *(const float2*)(rowm + 2 * h);
                fs += v.x + v.y;
                fm = fmaf(v.x, mk.x, fm);
                fm = fmaf(v.y, mk.y, fm);
            }
        }
        protos[((size_t)b * PPAD + t) * CC + c] = fs * (1.f / 36.f);
        red[t] = fm;
        __syncthreads();
        for (int off = 128; off > 0; off >>= 1) {
            if (t < off) red[t] += red[t + off];
            __syncthreads();
        }
        if (t == 0) protos[((size_t)b * PPAD + 256) * CC + c] = red[0];
    } else {
        int b = blk - BB * CC;
        int gy = t >> 4, gx = t & 15;
        const float* mb = sup_mask + (size_t)b * HWW;
        const float* gb = true_bg  + (size_t)b * HWW;
        int base = gy * 6 * WW + gx * 6;
        float ms = 0.f, bs = 0.f;
        for (int r = 0; r < 6; ++r) {
            const float* rowm = mb + base + r * WW;
            const float* rowg = gb + base + r * WW;
#pragma unroll
            for (int h = 0; h < 3; ++h) {
                float2 mk = *(const float2*)(rowm + 2 * h);
                float2 bg2 = *(const float2*)(rowg + 2 * h);
                ms += mk.x + mk.y;
                bs += bg2.x + bg2.y;
            }
        }
        float mmean = ms * (1.f / 36.f);
        float bmean = bs * (1.f / 36.f);
        validf[b * PPAD + t] = (mmean > THRESH && bmean < 0.5f) ? 1.f : 0.f;
        if (t == 0) validf[b * PPAD + 256] = 1.f;
        red[t] = ms;
        __syncthreads();
        for (int off = 128; off > 0; off >>= 1) {
            if (t < off) red[t] += red[t + off];
            __syncthreads();
        }
        if (t == 0) masksum[b] = red[0];
    }
}

// ------- kernel 2: finish gproto + normalize + emit fp16 proto image --------
// Pimg layout (fp16): [B][16 kstep][2 khalf][8 tile][32 col][8 e]
__global__ void k2_norm(float* __restrict__ protos,
                        const float* __restrict__ masksum,
                        unsigned short* __restrict__ Pimg) {
    int bp = blockIdx.x;
    int b = bp / PPAD;
    int p = bp - b * PPAD;
    int t = threadIdx.x;            // channel
    float v = protos[((size_t)b * PPAD + p) * CC + t];
    if (p == 256) v = v / (masksum[b] + 1e-5f);
    __shared__ float red[256];
    red[t] = v * v;
    __syncthreads();
    for (int off = 128; off > 0; off >>= 1) {
        if (t < off) red[t] += red[t + off];
        __syncthreads();
    }
    float norm = sqrtf(red[0]);
    float vn = v / fmaxf(norm, NORM_EPS);
    protos[((size_t)b * PPAD + p) * CC + t] = vn;
    if (p < NLOC) {
        H16 h; h.f = (_Float16)vn;            // RNE, err 2^-11
        int kstep = t >> 4, khalf = (t >> 3) & 1, e = t & 7;
        int tile = p >> 5, col = p & 31;
        size_t idx = ((((size_t)b * 16 + kstep) * 2 + khalf) * 8 + tile) * 256
                     + col * 8 + e;
        Pimg[idx] = h.u;
    }
}

// ---------------- kernel 3: MFMA dists + masked softmax + weighted sum ------
// CONVERT PHASE DELETED (the serial latency chain that set T_block ~29us):
//  - q staged RAW via 8 x global_load_lds (r21-verified, zero VGPR, one
//    latency exposure);
//  - A-fragments built ON-THE-FLY in the marathon: 8 ds_read_b32 of raw fp32
//    (bank=col all lanes, 2-way h-pair = FREE) + 8 v_cvt per ks — each (ch,px)
//    converted exactly once;
//  - gproto preloaded to LDS (gpl): gac FMAs read broadcast-LDS, never global
//    (r13-r21 did 32 serialized GLOBAL gp loads per thread = the chain);
//  - nrm/gac accumulate in marathon lanes (lane(col,h) owns 128ch of px=col),
//    completed by one shfl_xor(32); red_n/red_g/convert-Qf all deleted.
// Marathon MFMA pattern + epilogue byte-identical to r13 (verified D-map).
__global__ __launch_bounds__(256, 4)
void k3_mfma(const float* __restrict__ qry,
             const unsigned short* __restrict__ Pimg,
             const float* __restrict__ protos_n,
             const float* __restrict__ validf,
             float* __restrict__ out) {
    __shared__ alignas(16) float Qraw[256 * 32];   // [ch][px32] = 32 KB
    __shared__ float gpl[256];                     // gproto_n, 1 KB
    __shared__ float rn_s[32], gd_s[32];
    __shared__ float S_l[4][32], N_l[4][32];

    int blk = blockIdx.x;
    int b = blk & 7;                  // batch <-> XCD affinity
    int tpx = blk >> 3;               // 0..287
    int px0 = tpx * 32;
    int t = threadIdx.x;              // 0..255
    int l = t & 63;
    int w = t >> 6;                   // wave 0..3
    int col = l & 31;                 // proto-col / pixel index in frag space
    int h = l >> 5;                   // k-half lane bit

    const float* qbase = qry + (size_t)b * CC * HWW;
    const float* gp = protos_n + ((size_t)b * PPAD + 256) * CC;
    const unsigned short* Pb = Pimg + (size_t)b * 65536;

    // hoisted epilogue operands
    float vf0 = validf[b * PPAD + w * 64 + col];
    float vf1 = validf[b * PPAD + w * 64 + 32 + col];

    // ---- stage: gproto -> LDS (1 load/thread) + raw q via global_load_lds --
    gpl[t] = gp[t];
    {
        char* dstbase = (char*)Qraw + w * 1024;   // wave-uniform; HW adds lane*16
#pragma unroll
        for (int i = 0; i < 8; ++i) {
            int F = i * 256 + t;                  // cell = ch*8 + pxq
            int ch = F >> 3, pxq = F & 7;
            __builtin_amdgcn_global_load_lds(
                (const void*)(qbase + (size_t)ch * HWW + px0 + pxq * 4),
                (void*)(dstbase + i * 4096), 16, 0, 0);
        }
    }
    __syncthreads();                  // drains stage; nothing else in flight

    // ---- marathon: 16 ks x {8 raw ds_read + cvt, 2 MFMA}; B 2-deep ----
    f32x16 acc[2];
#pragma unroll
    for (int i = 0; i < 16; ++i) { acc[0][i] = 0.f; acc[1][i] = 0.f; }
    f16x8 Bf[2][2];
    float nrm = 0.f, gac = 0.f;

#define LOADB(KS, BUF)                                                        \
    {                                                                         \
        _Pragma("unroll")                                                     \
        for (int ti = 0; ti < 2; ++ti)                                        \
            Bf[BUF][ti] = *(const f16x8*)(Pb +                                \
                ((((size_t)(KS) * 2 + h) * 8 + (w * 2 + ti)) * 32 + col) * 8);\
    }

    LOADB(0, 0);
    LOADB(1, 1);

#pragma unroll
    for (int ks = 0; ks < 16; ++ks) {
        int c0 = ks * 16 + h * 8;                 // this lane's 8 channels
        float qv[8];
#pragma unroll
        for (int i = 0; i < 8; ++i) qv[i] = Qraw[(c0 + i) * 32 + col];
        unsigned int us[8];
#pragma unroll
        for (int i = 0; i < 8; ++i) {
            H16 x; x.f = (_Float16)qv[i];         // RNE (r13 numerics)
            us[i] = x.u;
            nrm = fmaf(qv[i], qv[i], nrm);
            gac = fmaf(qv[i], gpl[c0 + i], gac);  // broadcast LDS, free
        }
        union { f16x8 v; unsigned int u[4]; } QA;
        QA.u[0] = us[0] | (us[1] << 16); QA.u[1] = us[2] | (us[3] << 16);
        QA.u[2] = us[4] | (us[5] << 16); QA.u[3] = us[6] | (us[7] << 16);
#pragma unroll
        for (int ti = 0; ti < 2; ++ti)
            acc[ti] = __builtin_amdgcn_mfma_f32_32x32x16_f16(QA.v, Bf[ks & 1][ti], acc[ti], 0, 0, 0);
        if (ks + 2 < 16) LOADB(ks + 2, ks & 1);
    }
#undef LOADB

    // ---- finish |q|^2 and gproto-dot: h-pair merge; px = col ----
    nrm += __shfl_xor(nrm, 32);
    gac += __shfl_xor(gac, 32);
    if (w == 0 && l < 32) {                       // all waves hold same values
        float rn = 1.f / fmaxf(sqrtf(nrm), NORM_EPS);
        rn_s[l] = rn;
        gd_s[l] = gac * rn;
    }
    __syncthreads();                  // rn_s/gd_s visible

    // ---- softmax epilogue (r13-verified) ----
    // D-map (m74/m101): proto = w*64 + ti*32 + col (col = lane&31);
    // row(px) = (r&3) + 8*(r>>2) + 4*h.
#pragma unroll
    for (int r = 0; r < 16; ++r) {
        int row = (r & 3) + 8 * (r >> 2) + 4 * h;
        float rnv = rn_s[row];
        float d0 = acc[0][r] * rnv;
        float d1 = acc[1][r] * rnv;
        float l0 = (vf0 != 0.f) ? d0 : -1e30f;
        float l1 = (vf1 != 0.f) ? d1 : -1e30f;
        float e0 = __expf(l0 - 1.1f);             // masked -> exactly 0
        float e1 = __expf(l1 - 1.1f);
        float s = e0 + e1;
        float nn = fmaf(e0, l0, e1 * l1);
#pragma unroll
        for (int m = 1; m < 32; m <<= 1) {        // reduce over 32 proto-cols
            s  += __shfl_xor(s, m);
            nn += __shfl_xor(nn, m);
        }
        if (col == 0) { S_l[w][row] = s; N_l[w][row] = nn; }
    }
    __syncthreads();

    // ---- final merge: 4 wave-partials + global proto (once), store ----
    if (t < 32) {
        float gdv = gd_s[t];
        float eg = __expf(gdv - 1.1f);
        float S = eg, N = eg * gdv;
#pragma unroll
        for (int i = 0; i < 4; ++i) { S += S_l[i][t]; N += N_l[i][t]; }
        out[(size_t)b * HWW + px0 + t] = N / S;
    }
}

extern "C" void kernel_launch(void* const* d_in, const int* in_sizes, int n_in,
                              void* d_out, int out_size, void* d_ws, size_t ws_size,
                              hipStream_t stream) {
    const float* qry = (const float*)d_in[0];
    const float* sup = (const float*)d_in[1];
    const float* msk = (const float*)d_in[2];
    const float* bg  = (const float*)d_in[3];
    float* out = (float*)d_out;

    float* ws = (float*)d_ws;
    float* protos  = ws;                                   // [B][257][256] f32
    float* validf  = protos + (size_t)BB * PPAD * CC;      // [B][257]
    float* masksum = validf + (size_t)BB * PPAD;           // [B]
    unsigned short* Pimg = (unsigned short*)(masksum + BB); // [B][16][2][8][32][8] fp16

    hipLaunchKernelGGL(k01, dim3(BB * CC + BB), dim3(256), 0, stream,
                       sup, msk, bg, protos, validf, masksum);
    hipLaunchKernelGGL(k2_norm, dim3(BB * PPAD), dim3(256), 0, stream, protos, masksum, Pimg);
    hipLaunchKernelGGL(k3_mfma, dim3(BB * (HWW / 32)), dim3(256), 0, stream,
                       qry, Pimg, protos, validf, out);
}